// Round 8
// baseline (463.001 us; speedup 1.0000x reference)
//
#include <hip/hip_runtime.h>

#define PADH 68   // row pitch (floats) for 64-col LDS tiles

typedef float v2f __attribute__((ext_vector_type(2)));

__device__ __forceinline__ v2f v2ld(const float* p) { return *(const v2f*)p; }   // 8B-aligned
__device__ __forceinline__ v2f v2fma(v2f a, v2f b, v2f c) { return __builtin_elementwise_fma(a, b, c); }
__device__ __forceinline__ v2f v2max0(v2f a) { v2f z = {0.f, 0.f}; return __builtin_elementwise_max(a, z); }

__device__ __forceinline__ float sigm_(float x) { return 1.0f / (1.0f + __expf(-x)); }
__device__ __forceinline__ float tanh_(float x) {
    x = fminf(fmaxf(x, -15.0f), 15.0f);
    const float e = __expf(2.0f * x);
    return (e - 1.0f) / (e + 1.0f);
}

// R7 structure (2 rows/block, 4 waves, wave-uniform weights -> s_load, packed
// fp32; 336 us) + R8: edge-PAIR processing in phase B — one W2b/W2c row load
// feeds two edges' accumulators (halves the SMEM stream that stalls 2-wave/SIMD
// occupancy; doubles FMA per load).
__global__ __launch_bounds__(256, 2) void gnn_fused(
    const float* __restrict__ init_features,  // (B,32,3)
    const float* __restrict__ edge_weight,    // (B,992)
    const float* __restrict__ noise_info,     // (B,1)
    const float* __restrict__ hx_init,        // (B,32,64)
    const float* __restrict__ x_hat,
    const float* __restrict__ var_in,
    const float* __restrict__ W1a, const float* __restrict__ b1a,
    const float* __restrict__ W2a, const float* __restrict__ b2a,
    const float* __restrict__ W2b, const float* __restrict__ b2b,
    const float* __restrict__ W2c, const float* __restrict__ b2c,
    const float* __restrict__ W3a, const float* __restrict__ b3a,
    const float* __restrict__ W3b, const float* __restrict__ b3b,
    const float* __restrict__ W3c, const float* __restrict__ b3c,
    const float* __restrict__ Wih, const float* __restrict__ Whh,
    const float* __restrict__ bih, const float* __restrict__ bhh,
    const float* __restrict__ W4,  const float* __restrict__ b4,
    float* __restrict__ out)                  // (B,32,4)
{
    const int t  = threadIdx.x;
    const int w  = __builtin_amdgcn_readfirstlane(t >> 6); // wave id 0..3
    const int l  = t & 63;    // node slot = bl*32 + a
    const int bl = l >> 5;
    const int a  = l & 31;
    const int b0 = blockIdx.x * 2;
    const int bg = b0 + bl;

    __shared__ float s_edge[1984];        // [2][992]
    __shared__ float s_A1[64][PADH];
    __shared__ float s_B1[64][PADH];
    __shared__ float s_hx[64][PADH];
    __shared__ float s_nodes[64][8];
    __shared__ float s_part[4][64][9];

    for (int i = t; i < 1984; i += 256) s_edge[i] = edge_weight[(size_t)b0*992 + i];
    for (int i = t; i < 4096; i += 256) s_hx[i >> 6][i & 63] = hx_init[(size_t)b0*2048 + i];
    const float nw = noise_info[bg];
    const v2f nwp = {nw, nw};

    // ---- iteration-0 nodes: x_init(5) @ W1a(5,8) + b1a; wave w does channels w*2,w*2+1
    {
        const float* f = init_features + ((size_t)bg*32 + a)*3;
        const float xi0 = f[0], xi1 = f[1], xi2 = f[2];
        const float xi3 = x_hat[(size_t)bg*32 + a];
        const float xi4 = var_in[(size_t)bg*32 + a];
        #pragma unroll
        for (int cc = 0; cc < 2; ++cc) {
            const int c = w*2 + cc;
            float acc = b1a[c];
            acc = __builtin_fmaf(xi0, W1a[0*8+c], acc);
            acc = __builtin_fmaf(xi1, W1a[1*8+c], acc);
            acc = __builtin_fmaf(xi2, W1a[2*8+c], acc);
            acc = __builtin_fmaf(xi3, W1a[3*8+c], acc);
            acc = __builtin_fmaf(xi4, W1a[4*8+c], acc);
            s_nodes[l][c] = acc;
        }
    }
    __syncthreads();

    #pragma unroll 1
    for (int it = 0; it < 3; ++it) {
        // ---- A: A1 = nodes@W2a[0:8]+b2a+nw*W2a[17]; B1 = nodes@W2a[8:16].
        //      wave w covers h = w*16..+15, packed over h-pairs. ----
        {
            float nd[8];
            *(float4*)&nd[0] = *(const float4*)&s_nodes[l][0];
            *(float4*)&nd[4] = *(const float4*)&s_nodes[l][4];
            const int h0 = w*16;
            v2f aA[8], aB[8];
            #pragma unroll
            for (int hp = 0; hp < 8; ++hp) {
                aA[hp] = v2fma(nwp, v2ld(&W2a[1088 + h0 + 2*hp]), v2ld(&b2a[h0 + 2*hp]));
                aB[hp] = (v2f){0.f, 0.f};
            }
            #pragma unroll
            for (int k = 0; k < 8; ++k) {
                const v2f ndk = {nd[k], nd[k]};
                #pragma unroll
                for (int hp = 0; hp < 8; ++hp) {
                    aA[hp] = v2fma(ndk, v2ld(&W2a[k*64     + h0 + 2*hp]), aA[hp]);
                    aB[hp] = v2fma(ndk, v2ld(&W2a[(8+k)*64 + h0 + 2*hp]), aB[hp]);
                }
            }
            #pragma unroll
            for (int hp = 0; hp < 8; ++hp) {
                *(v2f*)&s_A1[l][h0 + 2*hp] = aA[hp];   // 272l + even*4 bytes: 8B-aligned
                *(v2f*)&s_B1[l][h0 + 2*hp] = aB[hp];
            }
        }
        __syncthreads();

        // ---- B: edge MLP, PAIRED. Wave w: pair e -> (j1=w+8e, j2=w+8e+4).
        //      j1 ranges {0..27}, j2 {4..31}; j2==31 (w=3,e=3) skipped uniform. ----
        v2f accoutp[4];
        #pragma unroll
        for (int cp = 0; cp < 4; ++cp) accoutp[cp] = (v2f){0.f, 0.f};

        #pragma unroll 1
        for (int e = 0; e < 4; ++e) {
            const int j1 = w + 8*e;
            const int j2 = j1 + 4;
            const bool has2 = (j2 < 31);       // wave-uniform
            const int tb1 = (j1 < a) ? j1 : (j1 + 1);
            const int tb2 = (j2 < a) ? j2 : (j2 + 1);
            const float ew1 = s_edge[bl*992 + a*31 + j1];
            const float ew2 = has2 ? s_edge[bl*992 + a*31 + j2] : 0.0f;  // j2==31 index OOB
            const v2f ew1p = {ew1, ew1};
            const v2f ew2p = {ew2, ew2};

            v2f m2a[16], m2b[16];
            #pragma unroll
            for (int p = 0; p < 16; ++p) { m2a[p] = v2ld(&b2b[2*p]); m2b[p] = m2a[p]; }

            #pragma unroll 1
            for (int kb = 0; kb < 4; ++kb) {
                v2f m1a[8], m1b[8];
                #pragma unroll
                for (int hp = 0; hp < 8; ++hp) {
                    const int h = kb*16 + 2*hp;
                    const v2f base = v2ld(&s_A1[l][h]);
                    const v2f wv   = v2ld(&W2a[1024 + h]);   // shared between edges
                    m1a[hp] = v2max0(v2fma(ew1p, wv, base + v2ld(&s_B1[bl*32 + tb1][h])));
                    m1b[hp] = v2max0(v2fma(ew2p, wv, base + v2ld(&s_B1[bl*32 + tb2][h])));
                }
                #pragma unroll
                for (int kkp = 0; kkp < 8; ++kkp) {          // W2b rows uniform -> s_load,
                    const float* wr0 = &W2b[(kb*16 + 2*kkp)*32];  // each row feeds BOTH edges
                    const v2f mloA = {m1a[kkp].x, m1a[kkp].x};
                    const v2f mloB = {m1b[kkp].x, m1b[kkp].x};
                    #pragma unroll
                    for (int p = 0; p < 16; ++p) {
                        const v2f wv0 = v2ld(&wr0[2*p]);
                        m2a[p] = v2fma(mloA, wv0, m2a[p]);
                        m2b[p] = v2fma(mloB, wv0, m2b[p]);
                    }
                    const v2f mhiA = {m1a[kkp].y, m1a[kkp].y};
                    const v2f mhiB = {m1b[kkp].y, m1b[kkp].y};
                    #pragma unroll
                    for (int p = 0; p < 16; ++p) {
                        const v2f wv1 = v2ld(&wr0[32 + 2*p]);
                        m2a[p] = v2fma(mhiA, wv1, m2a[p]);
                        m2b[p] = v2fma(mhiB, wv1, m2b[p]);
                    }
                }
            }
            #pragma unroll
            for (int p = 0; p < 16; ++p) { m2a[p] = v2max0(m2a[p]); m2b[p] = v2max0(m2b[p]); }

            // L3: 32 -> 8, shared W2c loads
            v2f acc3a[4], acc3b[4];
            #pragma unroll
            for (int cp = 0; cp < 4; ++cp) { acc3a[cp] = v2ld(&b2c[2*cp]); acc3b[cp] = acc3a[cp]; }
            #pragma unroll
            for (int p = 0; p < 16; ++p) {
                const v2f mxA = {m2a[p].x, m2a[p].x}, myA = {m2a[p].y, m2a[p].y};
                const v2f mxB = {m2b[p].x, m2b[p].x}, myB = {m2b[p].y, m2b[p].y};
                #pragma unroll
                for (int cp = 0; cp < 4; ++cp) {
                    const v2f w0 = v2ld(&W2c[(2*p)*8   + 2*cp]);
                    const v2f w1 = v2ld(&W2c[(2*p+1)*8 + 2*cp]);
                    acc3a[cp] = v2fma(mxA, w0, acc3a[cp]);
                    acc3a[cp] = v2fma(myA, w1, acc3a[cp]);
                    acc3b[cp] = v2fma(mxB, w0, acc3b[cp]);
                    acc3b[cp] = v2fma(myB, w1, acc3b[cp]);
                }
            }
            #pragma unroll
            for (int cp = 0; cp < 4; ++cp) accoutp[cp] += v2max0(acc3a[cp]);
            if (has2) {                        // uniform branch
                #pragma unroll
                for (int cp = 0; cp < 4; ++cp) accoutp[cp] += v2max0(acc3b[cp]);
            }
        }
        // Each lane owns node l outright: write this wave's partial directly.
        #pragma unroll
        for (int cp = 0; cp < 4; ++cp) {
            s_part[w][l][2*cp]   = accoutp[cp].x;
            s_part[w][l][2*cp+1] = accoutp[cp].y;
        }
        __syncthreads();

        // ---- C: GRU; wave w owns channels c = w*16..+15, packed over k. ----
        v2f hp[32];                            // h state as 32 pairs (static idx only)
        #pragma unroll
        for (int q = 0; q < 16; ++q)
            *(float4*)&hp[2*q] = *(const float4*)&s_hx[l][q*4];
        float x8[8];
        #pragma unroll
        for (int k = 0; k < 8; ++k)
            x8[k] = s_part[0][l][k] + s_part[1][l][k] + s_part[2][l][k] + s_part[3][l][k];
        const v2f xp0 = {x8[0], x8[1]}, xp1 = {x8[2], x8[3]},
                  xp2 = {x8[4], x8[5]}, xp3 = {x8[6], x8[7]};
        __syncthreads();                       // all lanes captured h_old before writes

        #pragma unroll 1
        for (int cc = 0; cc < 16; ++cc) {
            const int c = w*16 + cc;           // uniform -> all weight reads s_load
            v2f ar = {0.f,0.f}, az = {0.f,0.f}, an = {0.f,0.f}, ah = {0.f,0.f};
            ar = v2fma(xp0, v2ld(&Wih[c*8+0]), ar);
            ar = v2fma(xp1, v2ld(&Wih[c*8+2]), ar);
            ar = v2fma(xp2, v2ld(&Wih[c*8+4]), ar);
            ar = v2fma(xp3, v2ld(&Wih[c*8+6]), ar);
            az = v2fma(xp0, v2ld(&Wih[(64+c)*8+0]), az);
            az = v2fma(xp1, v2ld(&Wih[(64+c)*8+2]), az);
            az = v2fma(xp2, v2ld(&Wih[(64+c)*8+4]), az);
            az = v2fma(xp3, v2ld(&Wih[(64+c)*8+6]), az);
            an = v2fma(xp0, v2ld(&Wih[(128+c)*8+0]), an);
            an = v2fma(xp1, v2ld(&Wih[(128+c)*8+2]), an);
            an = v2fma(xp2, v2ld(&Wih[(128+c)*8+4]), an);
            an = v2fma(xp3, v2ld(&Wih[(128+c)*8+6]), an);
            #pragma unroll
            for (int q = 0; q < 32; ++q) {
                ar = v2fma(hp[q], v2ld(&Whh[c*64       + 2*q]), ar);
                az = v2fma(hp[q], v2ld(&Whh[(64+c)*64  + 2*q]), az);
                ah = v2fma(hp[q], v2ld(&Whh[(128+c)*64 + 2*q]), ah);
            }
            const float r0 = bih[c]     + bhh[c]     + ar.x + ar.y;
            const float z0 = bih[64+c]  + bhh[64+c]  + az.x + az.y;
            const float n0 = bih[128+c]              + an.x + an.y;
            const float nh = bhh[128+c]              + ah.x + ah.y;
            const float rr = sigm_(r0);
            const float zz = sigm_(z0);
            const float nn = tanh_(n0 + rr*nh);
            const float hold = s_hx[l][c];     // still old: only this lane writes (l,c)
            s_hx[l][c] = (1.0f - zz)*nn + zz*hold;
        }
        __syncthreads();

        // ---- D: gru_read = hx_new @ W4 + b4; wave w does channels w*2, w*2+1 ----
        {
            const int c0 = w*2, c1 = w*2 + 1;
            float acc0 = b4[c0], acc1 = b4[c1];
            #pragma unroll
            for (int q = 0; q < 16; ++q) {
                const float4 hv = *(const float4*)&s_hx[l][q*4];
                acc0 = __builtin_fmaf(hv.x, W4[(q*4+0)*8 + c0], acc0);
                acc0 = __builtin_fmaf(hv.y, W4[(q*4+1)*8 + c0], acc0);
                acc0 = __builtin_fmaf(hv.z, W4[(q*4+2)*8 + c0], acc0);
                acc0 = __builtin_fmaf(hv.w, W4[(q*4+3)*8 + c0], acc0);
                acc1 = __builtin_fmaf(hv.x, W4[(q*4+0)*8 + c1], acc1);
                acc1 = __builtin_fmaf(hv.y, W4[(q*4+1)*8 + c1], acc1);
                acc1 = __builtin_fmaf(hv.z, W4[(q*4+2)*8 + c1], acc1);
                acc1 = __builtin_fmaf(hv.w, W4[(q*4+3)*8 + c1], acc1);
            }
            s_nodes[l][c0] = acc0;
            s_nodes[l][c1] = acc1;
        }
        __syncthreads();
    }

    // ---- final MLP: 8 -> 64 -> 32 -> 4 ----
    {
        float nd[8];
        *(float4*)&nd[0] = *(const float4*)&s_nodes[l][0];
        *(float4*)&nd[4] = *(const float4*)&s_nodes[l][4];
        #pragma unroll
        for (int hh = 0; hh < 16; ++hh) {
            const int hO = w*16 + hh;
            float acc = b3a[hO];
            #pragma unroll
            for (int k = 0; k < 8; ++k) acc = __builtin_fmaf(nd[k], W3a[k*64 + hO], acc);
            s_A1[l][hO] = acc;
        }
    }
    __syncthreads();
    {
        float acc[8];
        #pragma unroll
        for (int jj = 0; jj < 8; ++jj) acc[jj] = b3b[w*8 + jj];
        #pragma unroll
        for (int q = 0; q < 16; ++q) {
            const float4 v = *(const float4*)&s_A1[l][q*4];
            #pragma unroll
            for (int jj = 0; jj < 8; ++jj) {
                const int n = w*8 + jj;
                acc[jj] = __builtin_fmaf(v.x, W3b[(q*4+0)*32 + n], acc[jj]);
                acc[jj] = __builtin_fmaf(v.y, W3b[(q*4+1)*32 + n], acc[jj]);
                acc[jj] = __builtin_fmaf(v.z, W3b[(q*4+2)*32 + n], acc[jj]);
                acc[jj] = __builtin_fmaf(v.w, W3b[(q*4+3)*32 + n], acc[jj]);
            }
        }
        #pragma unroll
        for (int jj = 0; jj < 8; ++jj) s_B1[l][w*8 + jj] = acc[jj];
    }
    __syncthreads();
    {
        float acc = b3c[w];
        #pragma unroll
        for (int n = 0; n < 32; ++n)
            acc = __builtin_fmaf(s_B1[l][n], W3c[n*4 + w], acc);
        out[((size_t)bg*32 + a)*4 + w] = acc;
    }
}

extern "C" void kernel_launch(void* const* d_in, const int* in_sizes, int n_in,
                              void* d_out, int out_size, void* d_ws, size_t ws_size,
                              hipStream_t stream)
{
    const float* init_features = (const float*)d_in[0];
    const float* edge_weight   = (const float*)d_in[1];
    const float* noise_info    = (const float*)d_in[2];
    const float* hx_init       = (const float*)d_in[3];
    /* d_in[4] = cons — unused by the reference forward */
    const float* x_hat = (const float*)d_in[5];
    const float* var_i = (const float*)d_in[6];
    const float* W1a = (const float*)d_in[7];  const float* b1a = (const float*)d_in[8];
    const float* W2a = (const float*)d_in[9];  const float* b2a = (const float*)d_in[10];
    const float* W2b = (const float*)d_in[11]; const float* b2b = (const float*)d_in[12];
    const float* W2c = (const float*)d_in[13]; const float* b2c = (const float*)d_in[14];
    const float* W3a = (const float*)d_in[15]; const float* b3a = (const float*)d_in[16];
    const float* W3b = (const float*)d_in[17]; const float* b3b = (const float*)d_in[18];
    const float* W3c = (const float*)d_in[19]; const float* b3c = (const float*)d_in[20];
    const float* Wih = (const float*)d_in[21]; const float* Whh = (const float*)d_in[22];
    const float* bih = (const float*)d_in[23]; const float* bhh = (const float*)d_in[24];
    const float* W4  = (const float*)d_in[25]; const float* b4  = (const float*)d_in[26];

    gnn_fused<<<dim3(512), dim3(256), 0, stream>>>(
        init_features, edge_weight, noise_info, hx_init, x_hat, var_i,
        W1a, b1a, W2a, b2a, W2b, b2b, W2c, b2c,
        W3a, b3a, W3b, b3b, W3c, b3c,
        Wih, Whh, bih, bhh, W4, b4, (float*)d_out);
}

// Round 9
// 338.745 us; speedup vs baseline: 1.3668x; 1.3668x over previous
//
#include <hip/hip_runtime.h>

#define PADH 68   // row pitch (floats) for 64-col LDS tiles
#define SUMP 10   // s_sum pitch: EVEN so &s_sum[l][0] is 8B-aligned for v2 reads

typedef float v2f __attribute__((ext_vector_type(2)));

__device__ __forceinline__ v2f v2ld(const float* p) { return *(const v2f*)p; }   // 8B-aligned
__device__ __forceinline__ v2f v2fma(v2f a, v2f b, v2f c) { return __builtin_elementwise_fma(a, b, c); }
__device__ __forceinline__ v2f v2max0(v2f a) { v2f z = {0.f, 0.f}; return __builtin_elementwise_max(a, z); }

__device__ __forceinline__ float sigm_(float x) { return 1.0f / (1.0f + __expf(-x)); }
__device__ __forceinline__ float tanh_(float x) {
    x = fminf(fmaxf(x, -15.0f), 15.0f);
    const float e = __expf(2.0f * x);
    return (e - 1.0f) / (e + 1.0f);
}

// R9 = R7's packed-fp32 single-edge phases on R4's 8-wave partition.
// 2 batch rows/block, 512 threads = 8 waves; grid 512 -> 16 waves/CU target
// (R7's grid-capped 8). Per-thread work HALVES vs R7 (R8 lesson: never grow
// per-thread live state). launch_bounds(512,2): VGPR cap 256 — R4's (512,4)
// forced VGPR=60 + rematerialization (VALU-issue 318 us vs R7's 156).
// Cross-wave edge-sum: atomicAdd on LDS s_sum (R4-proven).
__global__ __launch_bounds__(512, 2) void gnn_fused(
    const float* __restrict__ init_features,  // (B,32,3)
    const float* __restrict__ edge_weight,    // (B,992)
    const float* __restrict__ noise_info,     // (B,1)
    const float* __restrict__ hx_init,        // (B,32,64)
    const float* __restrict__ x_hat,
    const float* __restrict__ var_in,
    const float* __restrict__ W1a, const float* __restrict__ b1a,
    const float* __restrict__ W2a, const float* __restrict__ b2a,
    const float* __restrict__ W2b, const float* __restrict__ b2b,
    const float* __restrict__ W2c, const float* __restrict__ c2c_unused_name_guard,
    const float* __restrict__ W3a, const float* __restrict__ b3a,
    const float* __restrict__ W3b, const float* __restrict__ b3b,
    const float* __restrict__ W3c, const float* __restrict__ b3c,
    const float* __restrict__ Wih, const float* __restrict__ Whh,
    const float* __restrict__ bih, const float* __restrict__ bhh,
    const float* __restrict__ W4,  const float* __restrict__ b4,
    float* __restrict__ out)                  // (B,32,4)
{
    const float* __restrict__ b2c = c2c_unused_name_guard;
    const int t  = threadIdx.x;
    const int w  = __builtin_amdgcn_readfirstlane(t >> 6); // wave id 0..7
    const int l  = t & 63;    // node slot = bl*32 + a
    const int bl = l >> 5;
    const int a  = l & 31;
    const int b0 = blockIdx.x * 2;
    const int bg = b0 + bl;

    __shared__ float s_edge[1984];        // [2][992]
    __shared__ float s_A1[64][PADH];
    __shared__ float s_B1[64][PADH];
    __shared__ float s_hx[64][PADH];
    __shared__ float s_nodes[64][8];
    __shared__ float s_sum[64][SUMP];     // cross-wave edge sums (ds atomicAdd)

    for (int i = t; i < 1984; i += 512) s_edge[i] = edge_weight[(size_t)b0*992 + i];
    for (int i = t; i < 4096; i += 512) s_hx[i >> 6][i & 63] = hx_init[(size_t)b0*2048 + i];
    const float nw = noise_info[bg];
    const v2f nwp = {nw, nw};

    // ---- iteration-0 nodes: x_init(5) @ W1a(5,8) + b1a; wave w does channel w
    {
        const float* f = init_features + ((size_t)bg*32 + a)*3;
        const float xi0 = f[0], xi1 = f[1], xi2 = f[2];
        const float xi3 = x_hat[(size_t)bg*32 + a];
        const float xi4 = var_in[(size_t)bg*32 + a];
        float acc = b1a[w];
        acc = __builtin_fmaf(xi0, W1a[0*8+w], acc);
        acc = __builtin_fmaf(xi1, W1a[1*8+w], acc);
        acc = __builtin_fmaf(xi2, W1a[2*8+w], acc);
        acc = __builtin_fmaf(xi3, W1a[3*8+w], acc);
        acc = __builtin_fmaf(xi4, W1a[4*8+w], acc);
        s_nodes[l][w] = acc;
    }
    __syncthreads();

    #pragma unroll 1
    for (int it = 0; it < 3; ++it) {
        // ---- zero s_sum (separated from B's atomics by the post-A barrier;
        //      from prev iter's C-reads by D's barrier) ----
        for (int i = t; i < 64*SUMP; i += 512) ((float*)s_sum)[i] = 0.0f;

        // ---- A: A1 = nodes@W2a[0:8]+b2a+nw*W2a[17]; B1 = nodes@W2a[8:16].
        //      wave w covers h = w*8..+7 (4 packed pairs, uniform indices). ----
        {
            float nd[8];
            *(float4*)&nd[0] = *(const float4*)&s_nodes[l][0];
            *(float4*)&nd[4] = *(const float4*)&s_nodes[l][4];
            const int h0 = w*8;
            v2f aA[4], aB[4];
            #pragma unroll
            for (int hp = 0; hp < 4; ++hp) {
                aA[hp] = v2fma(nwp, v2ld(&W2a[1088 + h0 + 2*hp]), v2ld(&b2a[h0 + 2*hp]));
                aB[hp] = (v2f){0.f, 0.f};
            }
            #pragma unroll
            for (int k = 0; k < 8; ++k) {
                const v2f ndk = {nd[k], nd[k]};
                #pragma unroll
                for (int hp = 0; hp < 4; ++hp) {
                    aA[hp] = v2fma(ndk, v2ld(&W2a[k*64     + h0 + 2*hp]), aA[hp]);
                    aB[hp] = v2fma(ndk, v2ld(&W2a[(8+k)*64 + h0 + 2*hp]), aB[hp]);
                }
            }
            #pragma unroll
            for (int hp = 0; hp < 4; ++hp) {
                *(v2f*)&s_A1[l][h0 + 2*hp] = aA[hp];
                *(v2f*)&s_B1[l][h0 + 2*hp] = aB[hp];
            }
        }
        __syncthreads();

        // ---- B: edge MLP; wave w handles edges j = w + 8i (i<4) of lane's node.
        //      j==31 (w=7,i=3) skipped wave-uniformly. Single-edge body (R8 lesson). ----
        v2f accoutp[4];
        #pragma unroll
        for (int cp = 0; cp < 4; ++cp) accoutp[cp] = (v2f){0.f, 0.f};

        #pragma unroll 1
        for (int i = 0; i < 4; ++i) {
            const int j = w + 8*i;            // uniform
            if (j < 31) {
                const int tbv = (j < a) ? j : (j + 1);
                const float ew = s_edge[bl*992 + a*31 + j];
                const v2f ewp = {ew, ew};
                v2f m2p[16];
                #pragma unroll
                for (int p = 0; p < 16; ++p) m2p[p] = v2ld(&b2b[2*p]);
                #pragma unroll 1
                for (int kb = 0; kb < 4; ++kb) {
                    v2f m1p[8];
                    #pragma unroll
                    for (int hp = 0; hp < 8; ++hp) {
                        const int h = kb*16 + 2*hp;
                        v2f tv = v2ld(&s_A1[l][h]) + v2ld(&s_B1[bl*32 + tbv][h]);
                        tv = v2fma(ewp, v2ld(&W2a[1024 + h]), tv);
                        m1p[hp] = v2max0(tv);
                    }
                    #pragma unroll
                    for (int kkp = 0; kkp < 8; ++kkp) {   // W2b rows: uniform -> s_load
                        const float* wr0 = &W2b[(kb*16 + 2*kkp)*32];
                        const v2f mlo = {m1p[kkp].x, m1p[kkp].x};
                        #pragma unroll
                        for (int p = 0; p < 16; ++p)
                            m2p[p] = v2fma(mlo, v2ld(&wr0[2*p]), m2p[p]);
                        const v2f mhi = {m1p[kkp].y, m1p[kkp].y};
                        #pragma unroll
                        for (int p = 0; p < 16; ++p)
                            m2p[p] = v2fma(mhi, v2ld(&wr0[32 + 2*p]), m2p[p]);
                    }
                }
                #pragma unroll
                for (int p = 0; p < 16; ++p) m2p[p] = v2max0(m2p[p]);
                // L3: 32 -> 8, packed over channel pairs
                v2f acc3[4];
                #pragma unroll
                for (int cp = 0; cp < 4; ++cp) acc3[cp] = v2ld(&b2c[2*cp]);
                #pragma unroll
                for (int p = 0; p < 16; ++p) {
                    const v2f mx = {m2p[p].x, m2p[p].x};
                    const v2f my = {m2p[p].y, m2p[p].y};
                    #pragma unroll
                    for (int cp = 0; cp < 4; ++cp) {
                        acc3[cp] = v2fma(mx, v2ld(&W2c[(2*p)*8   + 2*cp]), acc3[cp]);
                        acc3[cp] = v2fma(my, v2ld(&W2c[(2*p+1)*8 + 2*cp]), acc3[cp]);
                    }
                }
                #pragma unroll
                for (int cp = 0; cp < 4; ++cp) accoutp[cp] += v2max0(acc3[cp]);
            }
        }
        #pragma unroll
        for (int cp = 0; cp < 4; ++cp) {
            atomicAdd(&s_sum[l][2*cp],   accoutp[cp].x);
            atomicAdd(&s_sum[l][2*cp+1], accoutp[cp].y);
        }
        __syncthreads();

        // ---- C: GRU; wave w owns channels c = w*8..+7, packed over k. ----
        v2f hp[32];                            // h state as 32 pairs (static idx only)
        #pragma unroll
        for (int q = 0; q < 16; ++q)
            *(float4*)&hp[2*q] = *(const float4*)&s_hx[l][q*4];
        const v2f xp0 = v2ld(&s_sum[l][0]), xp1 = v2ld(&s_sum[l][2]),
                  xp2 = v2ld(&s_sum[l][4]), xp3 = v2ld(&s_sum[l][6]);
        __syncthreads();                       // all lanes captured h_old before writes

        #pragma unroll 1
        for (int cc = 0; cc < 8; ++cc) {
            const int c = w*8 + cc;            // uniform -> all weight reads s_load
            v2f ar = {0.f,0.f}, az = {0.f,0.f}, an = {0.f,0.f}, ah = {0.f,0.f};
            ar = v2fma(xp0, v2ld(&Wih[c*8+0]), ar);
            ar = v2fma(xp1, v2ld(&Wih[c*8+2]), ar);
            ar = v2fma(xp2, v2ld(&Wih[c*8+4]), ar);
            ar = v2fma(xp3, v2ld(&Wih[c*8+6]), ar);
            az = v2fma(xp0, v2ld(&Wih[(64+c)*8+0]), az);
            az = v2fma(xp1, v2ld(&Wih[(64+c)*8+2]), az);
            az = v2fma(xp2, v2ld(&Wih[(64+c)*8+4]), az);
            az = v2fma(xp3, v2ld(&Wih[(64+c)*8+6]), az);
            an = v2fma(xp0, v2ld(&Wih[(128+c)*8+0]), an);
            an = v2fma(xp1, v2ld(&Wih[(128+c)*8+2]), an);
            an = v2fma(xp2, v2ld(&Wih[(128+c)*8+4]), an);
            an = v2fma(xp3, v2ld(&Wih[(128+c)*8+6]), an);
            #pragma unroll
            for (int q = 0; q < 32; ++q) {
                ar = v2fma(hp[q], v2ld(&Whh[c*64       + 2*q]), ar);
                az = v2fma(hp[q], v2ld(&Whh[(64+c)*64  + 2*q]), az);
                ah = v2fma(hp[q], v2ld(&Whh[(128+c)*64 + 2*q]), ah);
            }
            const float r0 = bih[c]     + bhh[c]     + ar.x + ar.y;
            const float z0 = bih[64+c]  + bhh[64+c]  + az.x + az.y;
            const float n0 = bih[128+c]              + an.x + an.y;
            const float nh = bhh[128+c]              + ah.x + ah.y;
            const float rr = sigm_(r0);
            const float zz = sigm_(z0);
            const float nn = tanh_(n0 + rr*nh);
            const float hold = s_hx[l][c];     // still old: only this lane writes (l,c)
            s_hx[l][c] = (1.0f - zz)*nn + zz*hold;
        }
        __syncthreads();

        // ---- D: gru_read = hx_new @ W4 + b4; wave w does channel w ----
        {
            float acc = b4[w];
            #pragma unroll
            for (int q = 0; q < 16; ++q) {
                const float4 hv = *(const float4*)&s_hx[l][q*4];
                acc = __builtin_fmaf(hv.x, W4[(q*4+0)*8 + w], acc);
                acc = __builtin_fmaf(hv.y, W4[(q*4+1)*8 + w], acc);
                acc = __builtin_fmaf(hv.z, W4[(q*4+2)*8 + w], acc);
                acc = __builtin_fmaf(hv.w, W4[(q*4+3)*8 + w], acc);
            }
            s_nodes[l][w] = acc;
        }
        __syncthreads();
    }

    // ---- final MLP: 8 -> 64 -> 32 -> 4 ----
    {   // v1 = nodes@W3a + b3a; wave w covers h = w*8..+7; store in s_A1
        float nd[8];
        *(float4*)&nd[0] = *(const float4*)&s_nodes[l][0];
        *(float4*)&nd[4] = *(const float4*)&s_nodes[l][4];
        #pragma unroll
        for (int hh = 0; hh < 8; ++hh) {
            const int hO = w*8 + hh;
            float acc = b3a[hO];
            #pragma unroll
            for (int k = 0; k < 8; ++k) acc = __builtin_fmaf(nd[k], W3a[k*64 + hO], acc);
            s_A1[l][hO] = acc;
        }
    }
    __syncthreads();
    {   // v2 = v1@W3b + b3b; wave w covers n = w*4..+3; store in s_B1
        float acc[4];
        #pragma unroll
        for (int jj = 0; jj < 4; ++jj) acc[jj] = b3b[w*4 + jj];
        #pragma unroll
        for (int q = 0; q < 16; ++q) {
            const float4 v = *(const float4*)&s_A1[l][q*4];
            #pragma unroll
            for (int jj = 0; jj < 4; ++jj) {
                const int n = w*4 + jj;
                acc[jj] = __builtin_fmaf(v.x, W3b[(q*4+0)*32 + n], acc[jj]);
                acc[jj] = __builtin_fmaf(v.y, W3b[(q*4+1)*32 + n], acc[jj]);
                acc[jj] = __builtin_fmaf(v.z, W3b[(q*4+2)*32 + n], acc[jj]);
                acc[jj] = __builtin_fmaf(v.w, W3b[(q*4+3)*32 + n], acc[jj]);
            }
        }
        #pragma unroll
        for (int jj = 0; jj < 4; ++jj) s_B1[l][w*4 + jj] = acc[jj];
    }
    __syncthreads();
    if (w < 4) {   // z = v2@W3c + b3c; wave w writes output channel w (NC=4)
        float acc = b3c[w];
        #pragma unroll
        for (int n = 0; n < 32; ++n)
            acc = __builtin_fmaf(s_B1[l][n], W3c[n*4 + w], acc);
        out[((size_t)bg*32 + a)*4 + w] = acc;
    }
}

extern "C" void kernel_launch(void* const* d_in, const int* in_sizes, int n_in,
                              void* d_out, int out_size, void* d_ws, size_t ws_size,
                              hipStream_t stream)
{
    const float* init_features = (const float*)d_in[0];
    const float* edge_weight   = (const float*)d_in[1];
    const float* noise_info    = (const float*)d_in[2];
    const float* hx_init       = (const float*)d_in[3];
    /* d_in[4] = cons — unused by the reference forward */
    const float* x_hat = (const float*)d_in[5];
    const float* var_i = (const float*)d_in[6];
    const float* W1a = (const float*)d_in[7];  const float* b1a = (const float*)d_in[8];
    const float* W2a = (const float*)d_in[9];  const float* b2a = (const float*)d_in[10];
    const float* W2b = (const float*)d_in[11]; const float* b2b = (const float*)d_in[12];
    const float* W2c = (const float*)d_in[13]; const float* b2c = (const float*)d_in[14];
    const float* W3a = (const float*)d_in[15]; const float* b3a = (const float*)d_in[16];
    const float* W3b = (const float*)d_in[17]; const float* b3b = (const float*)d_in[18];
    const float* W3c = (const float*)d_in[19]; const float* b3c = (const float*)d_in[20];
    const float* Wih = (const float*)d_in[21]; const float* Whh = (const float*)d_in[22];
    const float* bih = (const float*)d_in[23]; const float* bhh = (const float*)d_in[24];
    const float* W4  = (const float*)d_in[25]; const float* b4  = (const float*)d_in[26];

    gnn_fused<<<dim3(512), dim3(512), 0, stream>>>(
        init_features, edge_weight, noise_info, hx_init, x_hat, var_i,
        W1a, b1a, W2a, b2a, W2b, b2b, W2c, b2c,
        W3a, b3a, W3b, b3b, W3c, b3c,
        Wih, Whh, bih, bhh, W4, b4, (float*)d_out);
}

// Round 11
// 298.006 us; speedup vs baseline: 1.5537x; 1.1367x over previous
//
#include <hip/hip_runtime.h>

#define PADH 68   // row pitch (floats) for 64-col fp32 LDS tiles
#define SUMP 10   // s_sum pitch (even -> 8B-aligned v2 reads)

typedef float  v2f   __attribute__((ext_vector_type(2)));
typedef float  f32x4 __attribute__((ext_vector_type(4)));
typedef __fp16 f16x8 __attribute__((ext_vector_type(8)));
typedef __fp16 f16x2 __attribute__((ext_vector_type(2)));

__device__ __forceinline__ v2f v2ld(const float* p) { return *(const v2f*)p; }
__device__ __forceinline__ v2f v2fma(v2f a, v2f b, v2f c) { return __builtin_elementwise_fma(a, b, c); }
__device__ __forceinline__ v2f v2max0(v2f a) { v2f z = {0.f, 0.f}; return __builtin_elementwise_max(a, z); }

__device__ __forceinline__ float sigm_(float x) { return 1.0f / (1.0f + __expf(-x)); }
__device__ __forceinline__ float tanh_(float x) {
    x = fminf(fmaxf(x, -15.0f), 15.0f);
    const float e = __expf(2.0f * x);
    return (e - 1.0f) / (e + 1.0f);
}

// pack 8 relu'd fp32 (4 pairs) into an fp16 MFMA fragment
__device__ __forceinline__ f16x8 mk_frag(v2f m0, v2f m1, v2f m2, v2f m3) {
    f16x2 c0 = __builtin_amdgcn_cvt_pkrtz(m0.x, m0.y);
    f16x2 c1 = __builtin_amdgcn_cvt_pkrtz(m1.x, m1.y);
    f16x2 c2 = __builtin_amdgcn_cvt_pkrtz(m2.x, m2.y);
    f16x2 c3 = __builtin_amdgcn_cvt_pkrtz(m3.x, m3.y);
    return (f16x8){c0.x, c0.y, c1.x, c1.y, c2.x, c2.y, c3.x, c3.y};
}

// m1 8-k chunk: relu(A1[a][k..]+B1[tb][k..]+ew*W2a17[k..]) -> f16 frag chunk
__device__ __forceinline__ f16x8 m1_chunk(const float* pA, const float* pB,
                                          const float* pw, v2f ewp) {
    v2f m0 = v2max0(v2fma(ewp, v2ld(pw + 0), v2ld(pA + 0) + v2ld(pB + 0)));
    v2f m1 = v2max0(v2fma(ewp, v2ld(pw + 2), v2ld(pA + 2) + v2ld(pB + 2)));
    v2f m2 = v2max0(v2fma(ewp, v2ld(pw + 4), v2ld(pA + 4) + v2ld(pB + 4)));
    v2f m3 = v2max0(v2fma(ewp, v2ld(pw + 6), v2ld(pA + 6) + v2ld(pB + 6)));
    return mk_frag(m0, m1, m2, m3);
}

// R9 structure (2 rows/block, 8 waves, wave-uniform weights, packed fp32;
// 274 us) with phase B's L2/L3 moved to fp16 MFMA (f32 accumulate).
// Edge slots: 2048/block (2x992 + 64 masked dummies); wave w owns 16 M-tiles
// of 16 edges. m1 is built IN-REGISTER in A-frag layout (edge=lane&15,
// k=(lane>>4)*8 and +32) -> no LDS bounce for m1; 1KB/wave bounce for m2.
// Frag layouts: A[m=l&15][k=(l>>4)*8+j]; B[k=(l>>4)*8+j][n=l&15];
// D[row m=(l>>4)*4+r][col n=l&15] (D is HW-verified per m89).
// R10 fix: all fp16 vector types use __fp16 (cvt_pkrtz returns __fp16 vec;
// clang refuses _Float16 <-> __fp16 vector init).
__global__ __launch_bounds__(512, 2) void gnn_fused(
    const float* __restrict__ init_features,  // (B,32,3)
    const float* __restrict__ edge_weight,    // (B,992)
    const float* __restrict__ noise_info,     // (B,1)
    const float* __restrict__ hx_init,        // (B,32,64)
    const float* __restrict__ x_hat,
    const float* __restrict__ var_in,
    const float* __restrict__ W1a, const float* __restrict__ b1a,
    const float* __restrict__ W2a, const float* __restrict__ b2a,
    const float* __restrict__ W2b, const float* __restrict__ b2b,
    const float* __restrict__ W2c, const float* __restrict__ b2c,
    const float* __restrict__ W3a, const float* __restrict__ b3a,
    const float* __restrict__ W3b, const float* __restrict__ b3b,
    const float* __restrict__ W3c, const float* __restrict__ b3c,
    const float* __restrict__ Wih, const float* __restrict__ Whh,
    const float* __restrict__ bih, const float* __restrict__ bhh,
    const float* __restrict__ W4,  const float* __restrict__ b4,
    float* __restrict__ out)                  // (B,32,4)
{
    const int t  = threadIdx.x;
    const int w  = __builtin_amdgcn_readfirstlane(t >> 6); // wave id 0..7
    const int l  = t & 63;    // lane; also node slot = bl*32 + a for A/C/D
    const int bl = l >> 5;
    const int a  = l & 31;
    const int lm = l & 15;    // frag row/col selector
    const int lq = l >> 4;    // frag k-group 0..3
    const int b0 = blockIdx.x * 2;
    const int bg = b0 + bl;

    __shared__ float  s_edge[1984];       // [2][992]
    __shared__ float  s_A1[64][PADH];
    __shared__ float  s_B1[64][PADH];
    __shared__ float  s_hx[64][PADH];
    __shared__ float  s_nodes[64][8];
    __shared__ float  s_sum[64][SUMP];    // cross-wave edge sums (ds atomics)
    __shared__ float  s_w17[64];          // W2a row 16 (edge-weight row)
    __shared__ __fp16 s_W2bT[32][64];     // [n][k] fp16
    __shared__ __fp16 s_W2cT[16][32];     // [c][n] fp16, c>=8 zero
    __shared__ __fp16 s_m2[8][16][40];    // per-wave m2 re-frag bounce

    // ---- one-time staging ----
    for (int i = t; i < 1984; i += 512) s_edge[i] = edge_weight[(size_t)b0*992 + i];
    for (int i = t; i < 4096; i += 512) s_hx[i >> 6][i & 63] = hx_init[(size_t)b0*2048 + i];
    if (t < 64) s_w17[t] = W2a[1024 + t];
    for (int i = t; i < 2048; i += 512) {           // W2b^T -> fp16
        const int n = i >> 6, k = i & 63;
        s_W2bT[n][k] = (__fp16)W2b[k*32 + n];
    }
    if (t < 512) {                                  // W2c^T -> fp16, pad c to 16
        const int c = t >> 5, n = t & 31;
        s_W2cT[c][n] = (c < 8) ? (__fp16)W2c[n*8 + c] : (__fp16)0.f;
    }
    const float nw = noise_info[bg];
    const v2f nwp = {nw, nw};
    const float b2b_l0 = b2b[lm], b2b_l1 = b2b[lm + 16];
    const float b2c_l  = (lm < 8) ? b2c[lm] : 0.f;

    // ---- iteration-0 nodes: x_init(5) @ W1a(5,8) + b1a; wave w does channel w
    {
        const float* f = init_features + ((size_t)bg*32 + a)*3;
        const float xi0 = f[0], xi1 = f[1], xi2 = f[2];
        const float xi3 = x_hat[(size_t)bg*32 + a];
        const float xi4 = var_in[(size_t)bg*32 + a];
        float acc = b1a[w];
        acc = __builtin_fmaf(xi0, W1a[0*8+w], acc);
        acc = __builtin_fmaf(xi1, W1a[1*8+w], acc);
        acc = __builtin_fmaf(xi2, W1a[2*8+w], acc);
        acc = __builtin_fmaf(xi3, W1a[3*8+w], acc);
        acc = __builtin_fmaf(xi4, W1a[4*8+w], acc);
        s_nodes[l][w] = acc;
    }
    __syncthreads();

    #pragma unroll 1
    for (int it = 0; it < 3; ++it) {
        // ---- zero s_sum (post-A barrier separates from B's atomics) ----
        for (int i = t; i < 64*SUMP; i += 512) ((float*)s_sum)[i] = 0.0f;

        // ---- A: A1 = nodes@W2a[0:8]+b2a+nw*W2a[17]; B1 = nodes@W2a[8:16].
        //      wave w covers h = w*8..+7 (uniform weight indices). ----
        {
            float nd[8];
            *(float4*)&nd[0] = *(const float4*)&s_nodes[l][0];
            *(float4*)&nd[4] = *(const float4*)&s_nodes[l][4];
            const int h0 = w*8;
            v2f aA[4], aB[4];
            #pragma unroll
            for (int hp = 0; hp < 4; ++hp) {
                aA[hp] = v2fma(nwp, v2ld(&W2a[1088 + h0 + 2*hp]), v2ld(&b2a[h0 + 2*hp]));
                aB[hp] = (v2f){0.f, 0.f};
            }
            #pragma unroll
            for (int k = 0; k < 8; ++k) {
                const v2f ndk = {nd[k], nd[k]};
                #pragma unroll
                for (int hp = 0; hp < 4; ++hp) {
                    aA[hp] = v2fma(ndk, v2ld(&W2a[k*64     + h0 + 2*hp]), aA[hp]);
                    aB[hp] = v2fma(ndk, v2ld(&W2a[(8+k)*64 + h0 + 2*hp]), aB[hp]);
                }
            }
            #pragma unroll
            for (int hp = 0; hp < 4; ++hp) {
                *(v2f*)&s_A1[l][h0 + 2*hp] = aA[hp];
                *(v2f*)&s_B1[l][h0 + 2*hp] = aB[hp];
            }
        }
        __syncthreads();

        // ---- B: edge MLP via fp16 MFMA. Wave w owns slots [w*256, w*256+256). ----
        {
            // hoist B-frags (re-loaded each iteration to limit live range)
            const f16x8 Wb00 = *(const f16x8*)&s_W2bT[lm     ][     lq*8];
            const f16x8 Wb01 = *(const f16x8*)&s_W2bT[lm     ][32 + lq*8];
            const f16x8 Wb10 = *(const f16x8*)&s_W2bT[16 + lm][     lq*8];
            const f16x8 Wb11 = *(const f16x8*)&s_W2bT[16 + lm][32 + lq*8];
            const f16x8 Wcf  = *(const f16x8*)&s_W2cT[lm][lq*8];

            #pragma unroll 1
            for (int tt = 0; tt < 16; ++tt) {
                // this lane's edge for the A-fragment: m = lm
                const int slot = w*256 + tt*16 + lm;
                const int bls  = slot >> 10;
                const int e    = slot & 1023;
                const bool ok  = (e < 992);
                const int ae   = (e * 2115) >> 16;          // e/31, exact for e<992
                const int jj   = e - ae*31;
                const int rA   = ok ? (bls*32 + ae) : 0;    // clamp OOB dummies
                const int rB   = ok ? (bls*32 + ((jj < ae) ? jj : jj + 1)) : 0;
                const float ew = ok ? s_edge[bls*992 + e] : 0.f;
                const v2f ewp  = {ew, ew};

                // m1 A-frags, built directly in registers (layout matches)
                const f16x8 a0 = m1_chunk(&s_A1[rA][lq*8],      &s_B1[rB][lq*8],
                                          &s_w17[lq*8],         ewp);
                const f16x8 a1 = m1_chunk(&s_A1[rA][32 + lq*8], &s_B1[rB][32 + lq*8],
                                          &s_w17[32 + lq*8],    ewp);

                f32x4 acc0 = {0.f,0.f,0.f,0.f}, acc1 = {0.f,0.f,0.f,0.f};
                acc0 = __builtin_amdgcn_mfma_f32_16x16x32_f16(a0, Wb00, acc0, 0, 0, 0);
                acc0 = __builtin_amdgcn_mfma_f32_16x16x32_f16(a1, Wb01, acc0, 0, 0, 0);
                acc1 = __builtin_amdgcn_mfma_f32_16x16x32_f16(a0, Wb10, acc1, 0, 0, 0);
                acc1 = __builtin_amdgcn_mfma_f32_16x16x32_f16(a1, Wb11, acc1, 0, 0, 0);

                // m2 = relu(acc + b2b) -> f16, bounce through LDS to re-fragment
                #pragma unroll
                for (int r = 0; r < 4; ++r) {
                    s_m2[w][lq*4 + r][lm]      = (__fp16)fmaxf(acc0[r] + b2b_l0, 0.f);
                    s_m2[w][lq*4 + r][16 + lm] = (__fp16)fmaxf(acc1[r] + b2b_l1, 0.f);
                }
                const f16x8 a3 = *(const f16x8*)&s_m2[w][lm][lq*8];
                f32x4 acc3 = {0.f,0.f,0.f,0.f};
                acc3 = __builtin_amdgcn_mfma_f32_16x16x32_f16(a3, Wcf, acc3, 0, 0, 0);

                // epilogue: c = lm (<8 valid); rows = edges lq*4+r; run-combine
                if (lm < 8) {
                    float vals[4]; int an[4];
                    #pragma unroll
                    for (int r = 0; r < 4; ++r) {
                        const int sl  = w*256 + tt*16 + lq*4 + r;
                        const int bl2 = sl >> 10;
                        const int e2  = sl & 1023;
                        const int a2  = (e2 * 2115) >> 16;
                        an[r]   = (e2 < 992) ? (bl2*32 + a2) : -1;
                        vals[r] = fmaxf(acc3[r] + b2c_l, 0.f);
                    }
                    float run = vals[0]; int ra = an[0];
                    #pragma unroll
                    for (int r = 1; r < 4; ++r) {
                        if (an[r] == ra) { run += vals[r]; }
                        else {
                            if (ra >= 0) atomicAdd(&s_sum[ra][lm], run);
                            run = vals[r]; ra = an[r];
                        }
                    }
                    if (ra >= 0) atomicAdd(&s_sum[ra][lm], run);
                }
            }
        }
        __syncthreads();

        // ---- C: GRU; wave w owns channels c = w*8..+7, packed over k. ----
        v2f hp[32];
        #pragma unroll
        for (int q = 0; q < 16; ++q)
            *(float4*)&hp[2*q] = *(const float4*)&s_hx[l][q*4];
        const v2f xp0 = v2ld(&s_sum[l][0]), xp1 = v2ld(&s_sum[l][2]),
                  xp2 = v2ld(&s_sum[l][4]), xp3 = v2ld(&s_sum[l][6]);
        __syncthreads();                       // all lanes captured h_old before writes

        #pragma unroll 1
        for (int cc = 0; cc < 8; ++cc) {
            const int c = w*8 + cc;            // uniform -> all weight reads s_load
            v2f ar = {0.f,0.f}, az = {0.f,0.f}, an = {0.f,0.f}, ah = {0.f,0.f};
            ar = v2fma(xp0, v2ld(&Wih[c*8+0]), ar);
            ar = v2fma(xp1, v2ld(&Wih[c*8+2]), ar);
            ar = v2fma(xp2, v2ld(&Wih[c*8+4]), ar);
            ar = v2fma(xp3, v2ld(&Wih[c*8+6]), ar);
            az = v2fma(xp0, v2ld(&Wih[(64+c)*8+0]), az);
            az = v2fma(xp1, v2ld(&Wih[(64+c)*8+2]), az);
            az = v2fma(xp2, v2ld(&Wih[(64+c)*8+4]), az);
            az = v2fma(xp3, v2ld(&Wih[(64+c)*8+6]), az);
            an = v2fma(xp0, v2ld(&Wih[(128+c)*8+0]), an);
            an = v2fma(xp1, v2ld(&Wih[(128+c)*8+2]), an);
            an = v2fma(xp2, v2ld(&Wih[(128+c)*8+4]), an);
            an = v2fma(xp3, v2ld(&Wih[(128+c)*8+6]), an);
            #pragma unroll
            for (int q = 0; q < 32; ++q) {
                ar = v2fma(hp[q], v2ld(&Whh[c*64       + 2*q]), ar);
                az = v2fma(hp[q], v2ld(&Whh[(64+c)*64  + 2*q]), az);
                ah = v2fma(hp[q], v2ld(&Whh[(128+c)*64 + 2*q]), ah);
            }
            const float r0 = bih[c]     + bhh[c]     + ar.x + ar.y;
            const float z0 = bih[64+c]  + bhh[64+c]  + az.x + az.y;
            const float n0 = bih[128+c]              + an.x + an.y;
            const float nh = bhh[128+c]              + ah.x + ah.y;
            const float rr = sigm_(r0);
            const float zz = sigm_(z0);
            const float nn = tanh_(n0 + rr*nh);
            const float hold = s_hx[l][c];     // still old: only this lane writes (l,c)
            s_hx[l][c] = (1.0f - zz)*nn + zz*hold;
        }
        __syncthreads();

        // ---- D: gru_read = hx_new @ W4 + b4; wave w does channel w ----
        {
            float acc = b4[w];
            #pragma unroll
            for (int q = 0; q < 16; ++q) {
                const float4 hv = *(const float4*)&s_hx[l][q*4];
                acc = __builtin_fmaf(hv.x, W4[(q*4+0)*8 + w], acc);
                acc = __builtin_fmaf(hv.y, W4[(q*4+1)*8 + w], acc);
                acc = __builtin_fmaf(hv.z, W4[(q*4+2)*8 + w], acc);
                acc = __builtin_fmaf(hv.w, W4[(q*4+3)*8 + w], acc);
            }
            s_nodes[l][w] = acc;
        }
        __syncthreads();
    }

    // ---- final MLP: 8 -> 64 -> 32 -> 4 ----
    {   // v1 = nodes@W3a + b3a; wave w covers h = w*8..+7; store in s_A1
        float nd[8];
        *(float4*)&nd[0] = *(const float4*)&s_nodes[l][0];
        *(float4*)&nd[4] = *(const float4*)&s_nodes[l][4];
        #pragma unroll
        for (int hh = 0; hh < 8; ++hh) {
            const int hO = w*8 + hh;
            float acc = b3a[hO];
            #pragma unroll
            for (int k = 0; k < 8; ++k) acc = __builtin_fmaf(nd[k], W3a[k*64 + hO], acc);
            s_A1[l][hO] = acc;
        }
    }
    __syncthreads();
    {   // v2 = v1@W3b + b3b; wave w covers n = w*4..+3; store in s_B1
        float acc[4];
        #pragma unroll
        for (int jj = 0; jj < 4; ++jj) acc[jj] = b3b[w*4 + jj];
        #pragma unroll
        for (int q = 0; q < 16; ++q) {
            const float4 v = *(const float4*)&s_A1[l][q*4];
            #pragma unroll
            for (int jj = 0; jj < 4; ++jj) {
                const int n = w*4 + jj;
                acc[jj] = __builtin_fmaf(v.x, W3b[(q*4+0)*32 + n], acc[jj]);
                acc[jj] = __builtin_fmaf(v.y, W3b[(q*4+1)*32 + n], acc[jj]);
                acc[jj] = __builtin_fmaf(v.z, W3b[(q*4+2)*32 + n], acc[jj]);
                acc[jj] = __builtin_fmaf(v.w, W3b[(q*4+3)*32 + n], acc[jj]);
            }
        }
        #pragma unroll
        for (int jj = 0; jj < 4; ++jj) s_B1[l][w*4 + jj] = acc[jj];
    }
    __syncthreads();
    if (w < 4) {   // z = v2@W3c + b3c; wave w writes output channel w (NC=4)
        float acc = b3c[w];
        #pragma unroll
        for (int n = 0; n < 32; ++n)
            acc = __builtin_fmaf(s_B1[l][n], W3c[n*4 + w], acc);
        out[((size_t)bg*32 + a)*4 + w] = acc;
    }
}

extern "C" void kernel_launch(void* const* d_in, const int* in_sizes, int n_in,
                              void* d_out, int out_size, void* d_ws, size_t ws_size,
                              hipStream_t stream)
{
    const float* init_features = (const float*)d_in[0];
    const float* edge_weight   = (const float*)d_in[1];
    const float* noise_info    = (const float*)d_in[2];
    const float* hx_init       = (const float*)d_in[3];
    /* d_in[4] = cons — unused by the reference forward */
    const float* x_hat = (const float*)d_in[5];
    const float* var_i = (const float*)d_in[6];
    const float* W1a = (const float*)d_in[7];  const float* b1a = (const float*)d_in[8];
    const float* W2a = (const float*)d_in[9];  const float* b2a = (const float*)d_in[10];
    const float* W2b = (const float*)d_in[11]; const float* b2b = (const float*)d_in[12];
    const float* W2c = (const float*)d_in[13]; const float* b2c = (const float*)d_in[14];
    const float* W3a = (const float*)d_in[15]; const float* b3a = (const float*)d_in[16];
    const float* W3b = (const float*)d_in[17]; const float* b3b = (const float*)d_in[18];
    const float* W3c = (const float*)d_in[19]; const float* b3c = (const float*)d_in[20];
    const float* Wih = (const float*)d_in[21]; const float* Whh = (const float*)d_in[22];
    const float* bih = (const float*)d_in[23]; const float* bhh = (const float*)d_in[24];
    const float* W4  = (const float*)d_in[25]; const float* b4  = (const float*)d_in[26];

    gnn_fused<<<dim3(512), dim3(512), 0, stream>>>(
        init_features, edge_weight, noise_info, hx_init, x_hat, var_i,
        W1a, b1a, W2a, b2a, W2b, b2b, W2c, b2c,
        W3a, b3a, W3b, b3b, W3c, b3c,
        Wih, Whh, bih, bhh, W4, b4, (float*)d_out);
}

// Round 12
// 293.551 us; speedup vs baseline: 1.5772x; 1.0152x over previous
//
#include <hip/hip_runtime.h>

#define PADH 68   // row pitch (floats) for 64-col fp32 LDS tiles
#define SUMP 10   // s_sum pitch (even -> 8B-aligned v2 reads)

typedef float  v2f   __attribute__((ext_vector_type(2)));
typedef float  f32x4 __attribute__((ext_vector_type(4)));
typedef __fp16 f16x8 __attribute__((ext_vector_type(8)));
typedef __fp16 f16x2 __attribute__((ext_vector_type(2)));

__device__ __forceinline__ v2f v2ld(const float* p) { return *(const v2f*)p; }
__device__ __forceinline__ v2f v2fma(v2f a, v2f b, v2f c) { return __builtin_elementwise_fma(a, b, c); }
__device__ __forceinline__ v2f v2max0(v2f a) { v2f z = {0.f, 0.f}; return __builtin_elementwise_max(a, z); }

__device__ __forceinline__ float sigm_(float x) { return 1.0f / (1.0f + __expf(-x)); }
__device__ __forceinline__ float tanh_(float x) {
    x = fminf(fmaxf(x, -15.0f), 15.0f);
    const float e = __expf(2.0f * x);
    return (e - 1.0f) / (e + 1.0f);
}

// pack 8 relu'd fp32 (4 pairs) into an fp16 MFMA fragment
__device__ __forceinline__ f16x8 mk_frag(v2f m0, v2f m1, v2f m2, v2f m3) {
    f16x2 c0 = __builtin_amdgcn_cvt_pkrtz(m0.x, m0.y);
    f16x2 c1 = __builtin_amdgcn_cvt_pkrtz(m1.x, m1.y);
    f16x2 c2 = __builtin_amdgcn_cvt_pkrtz(m2.x, m2.y);
    f16x2 c3 = __builtin_amdgcn_cvt_pkrtz(m3.x, m3.y);
    return (f16x8){c0.x, c0.y, c1.x, c1.y, c2.x, c2.y, c3.x, c3.y};
}

// m1 8-k chunk: relu(A1[a][k..]+B1[tb][k..]+ew*W2a17[k..]) -> f16 frag chunk
__device__ __forceinline__ f16x8 m1_chunk(const float* pA, const float* pB,
                                          const float* pw, v2f ewp) {
    v2f m0 = v2max0(v2fma(ewp, v2ld(pw + 0), v2ld(pA + 0) + v2ld(pB + 0)));
    v2f m1 = v2max0(v2fma(ewp, v2ld(pw + 2), v2ld(pA + 2) + v2ld(pB + 2)));
    v2f m2 = v2max0(v2fma(ewp, v2ld(pw + 4), v2ld(pA + 4) + v2ld(pB + 4)));
    v2f m3 = v2max0(v2fma(ewp, v2ld(pw + 6), v2ld(pA + 6) + v2ld(pB + 6)));
    return mk_frag(m0, m1, m2, m3);
}

// R11 (fp16-MFMA edge MLP, 208 us) with s_edge dropped: edge weights read
// directly from global (one 64B line per 16-lane group, L1/L2-resident).
// LDS 80,384 -> 72,448 B => 2 blocks/CU restored (R11 fell to 1 block/CU:
// measured occupancy 23% despite 2x80,384 nominally fitting 160 KiB).
__global__ __launch_bounds__(512, 2) void gnn_fused(
    const float* __restrict__ init_features,  // (B,32,3)
    const float* __restrict__ edge_weight,    // (B,992)
    const float* __restrict__ noise_info,     // (B,1)
    const float* __restrict__ hx_init,        // (B,32,64)
    const float* __restrict__ x_hat,
    const float* __restrict__ var_in,
    const float* __restrict__ W1a, const float* __restrict__ b1a,
    const float* __restrict__ W2a, const float* __restrict__ b2a,
    const float* __restrict__ W2b, const float* __restrict__ b2b,
    const float* __restrict__ W2c, const float* __restrict__ b2c,
    const float* __restrict__ W3a, const float* __restrict__ b3a,
    const float* __restrict__ W3b, const float* __restrict__ b3b,
    const float* __restrict__ W3c, const float* __restrict__ b3c,
    const float* __restrict__ Wih, const float* __restrict__ Whh,
    const float* __restrict__ bih, const float* __restrict__ bhh,
    const float* __restrict__ W4,  const float* __restrict__ b4,
    float* __restrict__ out)                  // (B,32,4)
{
    const int t  = threadIdx.x;
    const int w  = __builtin_amdgcn_readfirstlane(t >> 6); // wave id 0..7
    const int l  = t & 63;    // lane; also node slot = bl*32 + a for A/C/D
    const int bl = l >> 5;
    const int a  = l & 31;
    const int lm = l & 15;    // frag row/col selector
    const int lq = l >> 4;    // frag k-group 0..3
    const int b0 = blockIdx.x * 2;
    const int bg = b0 + bl;

    __shared__ float  s_A1[64][PADH];
    __shared__ float  s_B1[64][PADH];
    __shared__ float  s_hx[64][PADH];
    __shared__ float  s_nodes[64][8];
    __shared__ float  s_sum[64][SUMP];    // cross-wave edge sums (ds atomics)
    __shared__ float  s_w17[64];          // W2a row 16 (edge-weight row)
    __shared__ __fp16 s_W2bT[32][64];     // [n][k] fp16
    __shared__ __fp16 s_W2cT[16][32];     // [c][n] fp16, c>=8 zero
    __shared__ __fp16 s_m2[8][16][40];    // per-wave m2 re-frag bounce

    // ---- one-time staging ----
    for (int i = t; i < 4096; i += 512) s_hx[i >> 6][i & 63] = hx_init[(size_t)b0*2048 + i];
    if (t < 64) s_w17[t] = W2a[1024 + t];
    for (int i = t; i < 2048; i += 512) {           // W2b^T -> fp16
        const int n = i >> 6, k = i & 63;
        s_W2bT[n][k] = (__fp16)W2b[k*32 + n];
    }
    if (t < 512) {                                  // W2c^T -> fp16, pad c to 16
        const int c = t >> 5, n = t & 31;
        s_W2cT[c][n] = (c < 8) ? (__fp16)W2c[n*8 + c] : (__fp16)0.f;
    }
    const float nw = noise_info[bg];
    const v2f nwp = {nw, nw};
    const float b2b_l0 = b2b[lm], b2b_l1 = b2b[lm + 16];
    const float b2c_l  = (lm < 8) ? b2c[lm] : 0.f;

    // ---- iteration-0 nodes: x_init(5) @ W1a(5,8) + b1a; wave w does channel w
    {
        const float* f = init_features + ((size_t)bg*32 + a)*3;
        const float xi0 = f[0], xi1 = f[1], xi2 = f[2];
        const float xi3 = x_hat[(size_t)bg*32 + a];
        const float xi4 = var_in[(size_t)bg*32 + a];
        float acc = b1a[w];
        acc = __builtin_fmaf(xi0, W1a[0*8+w], acc);
        acc = __builtin_fmaf(xi1, W1a[1*8+w], acc);
        acc = __builtin_fmaf(xi2, W1a[2*8+w], acc);
        acc = __builtin_fmaf(xi3, W1a[3*8+w], acc);
        acc = __builtin_fmaf(xi4, W1a[4*8+w], acc);
        s_nodes[l][w] = acc;
    }
    __syncthreads();

    #pragma unroll 1
    for (int it = 0; it < 3; ++it) {
        // ---- zero s_sum (post-A barrier separates from B's atomics) ----
        for (int i = t; i < 64*SUMP; i += 512) ((float*)s_sum)[i] = 0.0f;

        // ---- A: A1 = nodes@W2a[0:8]+b2a+nw*W2a[17]; B1 = nodes@W2a[8:16].
        //      wave w covers h = w*8..+7 (uniform weight indices). ----
        {
            float nd[8];
            *(float4*)&nd[0] = *(const float4*)&s_nodes[l][0];
            *(float4*)&nd[4] = *(const float4*)&s_nodes[l][4];
            const int h0 = w*8;
            v2f aA[4], aB[4];
            #pragma unroll
            for (int hp = 0; hp < 4; ++hp) {
                aA[hp] = v2fma(nwp, v2ld(&W2a[1088 + h0 + 2*hp]), v2ld(&b2a[h0 + 2*hp]));
                aB[hp] = (v2f){0.f, 0.f};
            }
            #pragma unroll
            for (int k = 0; k < 8; ++k) {
                const v2f ndk = {nd[k], nd[k]};
                #pragma unroll
                for (int hp = 0; hp < 4; ++hp) {
                    aA[hp] = v2fma(ndk, v2ld(&W2a[k*64     + h0 + 2*hp]), aA[hp]);
                    aB[hp] = v2fma(ndk, v2ld(&W2a[(8+k)*64 + h0 + 2*hp]), aB[hp]);
                }
            }
            #pragma unroll
            for (int hp = 0; hp < 4; ++hp) {
                *(v2f*)&s_A1[l][h0 + 2*hp] = aA[hp];
                *(v2f*)&s_B1[l][h0 + 2*hp] = aB[hp];
            }
        }
        __syncthreads();

        // ---- B: edge MLP via fp16 MFMA. Wave w owns slots [w*256, w*256+256). ----
        {
            // hoist B-frags (re-loaded each iteration to limit live range)
            const f16x8 Wb00 = *(const f16x8*)&s_W2bT[lm     ][     lq*8];
            const f16x8 Wb01 = *(const f16x8*)&s_W2bT[lm     ][32 + lq*8];
            const f16x8 Wb10 = *(const f16x8*)&s_W2bT[16 + lm][     lq*8];
            const f16x8 Wb11 = *(const f16x8*)&s_W2bT[16 + lm][32 + lq*8];
            const f16x8 Wcf  = *(const f16x8*)&s_W2cT[lm][lq*8];

            #pragma unroll 1
            for (int tt = 0; tt < 16; ++tt) {
                // this lane's edge for the A-fragment: m = lm
                const int slot = w*256 + tt*16 + lm;
                const int bls  = slot >> 10;
                const int e    = slot & 1023;
                const bool ok  = (e < 992);
                const int ae   = (e * 2115) >> 16;          // e/31, exact for e<992
                const int jj   = e - ae*31;
                const int rA   = ok ? (bls*32 + ae) : 0;    // clamp OOB dummies
                const int rB   = ok ? (bls*32 + ((jj < ae) ? jj : jj + 1)) : 0;
                // edge weight straight from global (64B line / 16-lane group)
                const float ew = ok ? edge_weight[(size_t)(b0 + bls)*992 + e] : 0.f;
                const v2f ewp  = {ew, ew};

                // m1 A-frags, built directly in registers (layout matches)
                const f16x8 a0 = m1_chunk(&s_A1[rA][lq*8],      &s_B1[rB][lq*8],
                                          &s_w17[lq*8],         ewp);
                const f16x8 a1 = m1_chunk(&s_A1[rA][32 + lq*8], &s_B1[rB][32 + lq*8],
                                          &s_w17[32 + lq*8],    ewp);

                f32x4 acc0 = {0.f,0.f,0.f,0.f}, acc1 = {0.f,0.f,0.f,0.f};
                acc0 = __builtin_amdgcn_mfma_f32_16x16x32_f16(a0, Wb00, acc0, 0, 0, 0);
                acc0 = __builtin_amdgcn_mfma_f32_16x16x32_f16(a1, Wb01, acc0, 0, 0, 0);
                acc1 = __builtin_amdgcn_mfma_f32_16x16x32_f16(a0, Wb10, acc1, 0, 0, 0);
                acc1 = __builtin_amdgcn_mfma_f32_16x16x32_f16(a1, Wb11, acc1, 0, 0, 0);

                // m2 = relu(acc + b2b) -> f16, bounce through LDS to re-fragment
                #pragma unroll
                for (int r = 0; r < 4; ++r) {
                    s_m2[w][lq*4 + r][lm]      = (__fp16)fmaxf(acc0[r] + b2b_l0, 0.f);
                    s_m2[w][lq*4 + r][16 + lm] = (__fp16)fmaxf(acc1[r] + b2b_l1, 0.f);
                }
                const f16x8 a3 = *(const f16x8*)&s_m2[w][lm][lq*8];
                f32x4 acc3 = {0.f,0.f,0.f,0.f};
                acc3 = __builtin_amdgcn_mfma_f32_16x16x32_f16(a3, Wcf, acc3, 0, 0, 0);

                // epilogue: c = lm (<8 valid); rows = edges lq*4+r; run-combine
                if (lm < 8) {
                    float vals[4]; int an[4];
                    #pragma unroll
                    for (int r = 0; r < 4; ++r) {
                        const int sl  = w*256 + tt*16 + lq*4 + r;
                        const int bl2 = sl >> 10;
                        const int e2  = sl & 1023;
                        const int a2  = (e2 * 2115) >> 16;
                        an[r]   = (e2 < 992) ? (bl2*32 + a2) : -1;
                        vals[r] = fmaxf(acc3[r] + b2c_l, 0.f);
                    }
                    float run = vals[0]; int ra = an[0];
                    #pragma unroll
                    for (int r = 1; r < 4; ++r) {
                        if (an[r] == ra) { run += vals[r]; }
                        else {
                            if (ra >= 0) atomicAdd(&s_sum[ra][lm], run);
                            run = vals[r]; ra = an[r];
                        }
                    }
                    if (ra >= 0) atomicAdd(&s_sum[ra][lm], run);
                }
            }
        }
        __syncthreads();

        // ---- C: GRU; wave w owns channels c = w*8..+7, packed over k. ----
        v2f hp[32];
        #pragma unroll
        for (int q = 0; q < 16; ++q)
            *(float4*)&hp[2*q] = *(const float4*)&s_hx[l][q*4];
        const v2f xp0 = v2ld(&s_sum[l][0]), xp1 = v2ld(&s_sum[l][2]),
                  xp2 = v2ld(&s_sum[l][4]), xp3 = v2ld(&s_sum[l][6]);
        __syncthreads();                       // all lanes captured h_old before writes

        #pragma unroll 1
        for (int cc = 0; cc < 8; ++cc) {
            const int c = w*8 + cc;            // uniform -> all weight reads s_load
            v2f ar = {0.f,0.f}, az = {0.f,0.f}, an = {0.f,0.f}, ah = {0.f,0.f};
            ar = v2fma(xp0, v2ld(&Wih[c*8+0]), ar);
            ar = v2fma(xp1, v2ld(&Wih[c*8+2]), ar);
            ar = v2fma(xp2, v2ld(&Wih[c*8+4]), ar);
            ar = v2fma(xp3, v2ld(&Wih[c*8+6]), ar);
            az = v2fma(xp0, v2ld(&Wih[(64+c)*8+0]), az);
            az = v2fma(xp1, v2ld(&Wih[(64+c)*8+2]), az);
            az = v2fma(xp2, v2ld(&Wih[(64+c)*8+4]), az);
            az = v2fma(xp3, v2ld(&Wih[(64+c)*8+6]), az);
            an = v2fma(xp0, v2ld(&Wih[(128+c)*8+0]), an);
            an = v2fma(xp1, v2ld(&Wih[(128+c)*8+2]), an);
            an = v2fma(xp2, v2ld(&Wih[(128+c)*8+4]), an);
            an = v2fma(xp3, v2ld(&Wih[(128+c)*8+6]), an);
            #pragma unroll
            for (int q = 0; q < 32; ++q) {
                ar = v2fma(hp[q], v2ld(&Whh[c*64       + 2*q]), ar);
                az = v2fma(hp[q], v2ld(&Whh[(64+c)*64  + 2*q]), az);
                ah = v2fma(hp[q], v2ld(&Whh[(128+c)*64 + 2*q]), ah);
            }
            const float r0 = bih[c]     + bhh[c]     + ar.x + ar.y;
            const float z0 = bih[64+c]  + bhh[64+c]  + az.x + az.y;
            const float n0 = bih[128+c]              + an.x + an.y;
            const float nh = bhh[128+c]              + ah.x + ah.y;
            const float rr = sigm_(r0);
            const float zz = sigm_(z0);
            const float nn = tanh_(n0 + rr*nh);
            const float hold = s_hx[l][c];     // still old: only this lane writes (l,c)
            s_hx[l][c] = (1.0f - zz)*nn + zz*hold;
        }
        __syncthreads();

        // ---- D: gru_read = hx_new @ W4 + b4; wave w does channel w ----
        {
            float acc = b4[w];
            #pragma unroll
            for (int q = 0; q < 16; ++q) {
                const float4 hv = *(const float4*)&s_hx[l][q*4];
                acc = __builtin_fmaf(hv.x, W4[(q*4+0)*8 + w], acc);
                acc = __builtin_fmaf(hv.y, W4[(q*4+1)*8 + w], acc);
                acc = __builtin_fmaf(hv.z, W4[(q*4+2)*8 + w], acc);
                acc = __builtin_fmaf(hv.w, W4[(q*4+3)*8 + w], acc);
            }
            s_nodes[l][w] = acc;
        }
        __syncthreads();
    }

    // ---- final MLP: 8 -> 64 -> 32 -> 4 ----
    {   // v1 = nodes@W3a + b3a; wave w covers h = w*8..+7; store in s_A1
        float nd[8];
        *(float4*)&nd[0] = *(const float4*)&s_nodes[l][0];
        *(float4*)&nd[4] = *(const float4*)&s_nodes[l][4];
        #pragma unroll
        for (int hh = 0; hh < 8; ++hh) {
            const int hO = w*8 + hh;
            float acc = b3a[hO];
            #pragma unroll
            for (int k = 0; k < 8; ++k) acc = __builtin_fmaf(nd[k], W3a[k*64 + hO], acc);
            s_A1[l][hO] = acc;
        }
    }
    __syncthreads();
    {   // v2 = v1@W3b + b3b; wave w covers n = w*4..+3; store in s_B1
        float acc[4];
        #pragma unroll
        for (int jj = 0; jj < 4; ++jj) acc[jj] = b3b[w*4 + jj];
        #pragma unroll
        for (int q = 0; q < 16; ++q) {
            const float4 v = *(const float4*)&s_A1[l][q*4];
            #pragma unroll
            for (int jj = 0; jj < 4; ++jj) {
                const int n = w*4 + jj;
                acc[jj] = __builtin_fmaf(v.x, W3b[(q*4+0)*32 + n], acc[jj]);
                acc[jj] = __builtin_fmaf(v.y, W3b[(q*4+1)*32 + n], acc[jj]);
                acc[jj] = __builtin_fmaf(v.z, W3b[(q*4+2)*32 + n], acc[jj]);
                acc[jj] = __builtin_fmaf(v.w, W3b[(q*4+3)*32 + n], acc[jj]);
            }
        }
        #pragma unroll
        for (int jj = 0; jj < 4; ++jj) s_B1[l][w*4 + jj] = acc[jj];
    }
    __syncthreads();
    if (w < 4) {   // z = v2@W3c + b3c; wave w writes output channel w (NC=4)
        float acc = b3c[w];
        #pragma unroll
        for (int n = 0; n < 32; ++n)
            acc = __builtin_fmaf(s_B1[l][n], W3c[n*4 + w], acc);
        out[((size_t)bg*32 + a)*4 + w] = acc;
    }
}

extern "C" void kernel_launch(void* const* d_in, const int* in_sizes, int n_in,
                              void* d_out, int out_size, void* d_ws, size_t ws_size,
                              hipStream_t stream)
{
    const float* init_features = (const float*)d_in[0];
    const float* edge_weight   = (const float*)d_in[1];
    const float* noise_info    = (const float*)d_in[2];
    const float* hx_init       = (const float*)d_in[3];
    /* d_in[4] = cons — unused by the reference forward */
    const float* x_hat = (const float*)d_in[5];
    const float* var_i = (const float*)d_in[6];
    const float* W1a = (const float*)d_in[7];  const float* b1a = (const float*)d_in[8];
    const float* W2a = (const float*)d_in[9];  const float* b2a = (const float*)d_in[10];
    const float* W2b = (const float*)d_in[11]; const float* b2b = (const float*)d_in[12];
    const float* W2c = (const float*)d_in[13]; const float* b2c = (const float*)d_in[14];
    const float* W3a = (const float*)d_in[15]; const float* b3a = (const float*)d_in[16];
    const float* W3b = (const float*)d_in[17]; const float* b3b = (const float*)d_in[18];
    const float* W3c = (const float*)d_in[19]; const float* b3c = (const float*)d_in[20];
    const float* Wih = (const float*)d_in[21]; const float* Whh = (const float*)d_in[22];
    const float* bih = (const float*)d_in[23]; const float* bhh = (const float*)d_in[24];
    const float* W4  = (const float*)d_in[25]; const float* b4  = (const float*)d_in[26];

    gnn_fused<<<dim3(512), dim3(512), 0, stream>>>(
        init_features, edge_weight, noise_info, hx_init, x_hat, var_i,
        W1a, b1a, W2a, b2a, W2b, b2b, W2c, b2c,
        W3a, b3a, W3b, b3b, W3c, b3c,
        Wih, Whh, bih, bhh, W4, b4, (float*)d_out);
}